// Round 7
// baseline (371.718 us; speedup 1.0000x reference)
//
#include <hip/hip_runtime.h>
#include <hip/hip_cooperative_groups.h>
namespace cg = cooperative_groups;

#define HH 256
#define WW 512
#define BQ 2
#define HWQ (HH*WW)
#define TW 68             // LDS tile cols (64 + 4 halo)
#define TH 12             // LDS tile rows (8 out + 4 halo)
#define CSTR 64           // LDS cell stride bytes (dense: contiguous 1KB tap reads)
#define TRL 20            // transpose stride (dwords)

#define RGASC 287.0f
#define CPC   1004.0f

typedef float f32x4 __attribute__((ext_vector_type(4)));
typedef short s16x8 __attribute__((ext_vector_type(8)));

// ---------------- static device scratch -------------------------------------
static __device__ uint4 g_Wm[25*64];          // packed A-fragments [tap][lane]
static __device__ float g_FC[HH*16];          // f_cor conv row-term [r][o]
static __device__ float g_S [HH*3*16];        // mean-correction  [r][k][o]
static __device__ float g_part[2][6*256];     // per-block partial sums (parity dbuf)
static __device__ float g_uvs[BQ*3*HWQ*2];    // stage state
static __device__ float g_Ts [BQ*3*HWQ];
static __device__ float g_qs [BQ*3*HWQ];

// Cell slot map (32 bf16): s0-11: [T0,q0,u0,v0, T1,q1,u1,v1, T2,q2,u2,v2]
// s12-14: KE0-2, s15: 0, s16-21: zT (T_k*u_k, T_k*v_k), s22-27: zq, s28-31: 0.
// Output rows o: 0-2 DIV_k, 3-5 TK_k, 6-8 QK_k, 9-14 (U0,V0,U1,V1,U2,V2), 15 pad.

__device__ __forceinline__ unsigned short f2bf(float f) {   // RNE f32->bf16
  unsigned int u = __builtin_bit_cast(unsigned int, f);
  u += 0x7fffu + ((u >> 16) & 1u);
  return (unsigned short)(u >> 16);
}
__device__ __forceinline__ float bflo(unsigned int d) {
  return __builtin_bit_cast(float, d << 16);
}
__device__ __forceinline__ float bfhi(unsigned int d) {
  return __builtin_bit_cast(float, d & 0xffff0000u);
}
__device__ __forceinline__ int foMap(int o) {   // full scalar-output channel
  return (o < 3) ? 6*o + 3 : (o < 6) ? 6*(o-3) + 4 : 6*(o-6) + 5;
}

// ---------------- the whole RK4 step as ONE cooperative kernel ---------------
// grid = 256 blocks (1/CU guaranteed co-resident) x 512 threads.
// Each block owns tile (ry, cx) for BOTH batch slices (bq unrolled).
__global__ __launch_bounds__(512, 2) void step_kernel(
    const float* __restrict__ ke_w,  const float* __restrict__ f_cor,
    const float* __restrict__ p_lev, const float* __restrict__ delta_p,
    const float* __restrict__ uv0,   const float* __restrict__ T0,
    const float* __restrict__ q0,    float* __restrict__ out,
    const int* __restrict__ dtp,
    const float* __restrict__ k_ss,  const float* __restrict__ k_vs,
    const float* __restrict__ k_sv,  const float* __restrict__ k_vv,
    const float* __restrict__ k_vs2)
{
  cg::grid_group grid = cg::this_grid();

  __shared__ __align__(16) char s_raw[TH*TW*CSTR];   // 52224 B; reused for transpose
  __shared__ float s_red[8][6];
  __shared__ float s_mean[6];

  const int bid = blockIdx.x;                   // 256 blocks: 8 cx x 32 ry
  const int cx  = bid & 7, ry = bid >> 3;
  const int c0  = cx << 6, R0 = ry << 3;
  const int tid = threadIdx.x;
  const int w   = tid >> 6;                     // wave 0..7 -> output row
  const int l   = tid & 63;
  const int r   = R0 + w, c = c0 + l;

  // ================= phase 0: base loads + T0 partials + weight pack ========
  float baseT[2][3], baseq[2][3], baseu[2][3], basev[2][3];
  float accT[2][3], accq[2][3], accu[2][3], accv[2][3];
  #pragma unroll
  for (int bq=0;bq<2;++bq)
    #pragma unroll
    for (int k=0;k<3;++k) {
      const int pix = ((bq*3+k)*HH + r)*WW + c;
      baseT[bq][k] = T0[pix]; baseq[bq][k] = q0[pix];
      float2 uvv = *(const float2*)(uv0 + 2*pix);
      baseu[bq][k] = uvv.x; basev[bq][k] = uvv.y;
    }
  #pragma unroll
  for (int bq=0;bq<2;++bq)
    #pragma unroll
    for (int k=0;k<3;++k) {
      float v = baseT[bq][k];
      #pragma unroll
      for (int off=32; off; off >>= 1) v += __shfl_down(v, off);
      if (l == 0) s_red[w][bq*3+k] = v;
    }
  __syncthreads();
  if (tid < 6) {
    float s = 0.f;
    #pragma unroll
    for (int ww=0;ww<8;++ww) s += s_red[ww][tid];
    g_part[0][tid*256 + ry*8 + cx] = s;
  }

  if (bid < 36) {                               // weight packing: 17984 items
    int tp = bid*512 + tid;
    if (tp < 1600) {                            // A-fragments g_Wm[t][lane]
      int ll = tp & 63, t = tp >> 6;
      int o = ll & 15, g = ll >> 4;
      int dy = t/5, dx = t%5;
      unsigned short h[8];
      #pragma unroll
      for (int e=0;e<8;++e) {
        int s = 8*g + e; float val = 0.f;
        if (o < 15) {
          int fo = foMap(o), vo = o - 9;
          if (s < 12) {
            int k = s >> 2, c4 = s & 3;
            if (c4 >= 2) {                      // u_k / v_k
              int j = 2*k + (c4-2);
              val = (o<9) ? k_vs[((fo*6+j)*5+dy)*5+dx]
                          : k_vv[((vo*6+j)*5+dy)*5+dx];
            } else {                            // T_k (+fold T_anom) / q_k
              int ifull = 6*k + ((c4==0) ? 4 : 5);
              val = (o<9) ? k_ss[((fo*19+ifull)*5+dy)*5+dx]
                          : k_sv[((vo*19+ifull)*5+dy)*5+dx];
              if (c4 == 0) {
                int ia = 6*k;                   // T_anom folded into T
                val += (o<9) ? k_ss[((fo*19+ia)*5+dy)*5+dx]
                             : k_sv[((vo*19+ia)*5+dy)*5+dx];
              }
            }
          } else if (s < 15) {                  // KE_k
            int ifull = 6*(s-12) + 1;
            val = (o<9) ? k_ss[((fo*19+ifull)*5+dy)*5+dx]
                        : k_sv[((vo*19+ifull)*5+dy)*5+dx];
          } else if (s >= 16 && s < 22) {       // zT_{k,c} -> output TK_k
            int k = (s-16)>>1, cc = (s-16)&1;
            if (o == 3+k) val = k_vs2[(((6*k+4)*6 + 2*k+cc)*5+dy)*5+dx];
          } else if (s >= 22 && s < 28) {       // zq_{k,c} -> output QK_k
            int k = (s-22)>>1, cc = (s-22)&1;
            if (o == 6+k) val = k_vs2[(((6*k+5)*6 + 2*k+cc)*5+dy)*5+dx];
          }
        }
        h[e] = f2bf(val);
      }
      uint4 wv;
      wv.x = h[0] | ((unsigned)h[1]<<16);  wv.y = h[2] | ((unsigned)h[3]<<16);
      wv.z = h[4] | ((unsigned)h[5]<<16);  wv.w = h[6] | ((unsigned)h[7]<<16);
      g_Wm[tp] = wv;
    } else if (tp < 1600 + HH*16) {             // g_FC[r][o]
      int e = tp - 1600;
      int o = e & 15, rr = e >> 4;
      float val = 0.f;
      if (o < 15) {
        int fo = foMap(o), vo = o - 9;
        for (int t=0;t<25;++t) {
          int dy = t/5, dx = t%5;
          int ar = rr + dy - 2;
          if (ar < 0 || ar >= HH) continue;
          float f = f_cor[ar];
          float wv = (o<9) ? k_ss[((fo*19+18)*5+dy)*5+dx]
                           : k_sv[((vo*19+18)*5+dy)*5+dx];
          val += wv * f;
        }
      }
      g_FC[e] = val;
    } else if (tp < 1600 + HH*16 + HH*3*16) {   // g_S[r][k][o]
      int e = tp - 1600 - HH*16;
      int o = e & 15; int rk = e >> 4;
      int k = rk % 3, rr = rk / 3;
      float val = 0.f;
      if (o < 15) {
        int fo = foMap(o), vo = o - 9;
        int ia = 6*k;                           // T_anom weight sum over valid taps
        for (int t=0;t<25;++t) {
          int dy = t/5, dx = t%5;
          int ar = rr + dy - 2;
          if (ar < 0 || ar >= HH) continue;
          val += (o<9) ? k_ss[((fo*19+ia)*5+dy)*5+dx]
                       : k_sv[((vo*19+ia)*5+dy)*5+dx];
        }
      }
      g_S[e] = val;
    }
  }

  const float dtf = (float)(*dtp);
  const float kw00=ke_w[0], kw01=ke_w[1], kw02=ke_w[2];
  const float kw10=ke_w[3], kw11=ke_w[4], kw12=ke_w[5];
  const float kw20=ke_w[6], kw21=ke_w[7], kw22=ke_w[8];
  const float fcv = f_cor[r];
  const float p0=p_lev[0], p1=p_lev[1], p2=p_lev[2];
  const float dp0=delta_p[0], dp1=delta_p[1], dp2=delta_p[2];
  const float r10 = 1.0f/(p1-p0), r20 = 1.0f/(p2-p0), r21 = 1.0f/(p2-p1);
  const float roc = RGASC/CPC;
  const float rp0 = 1.0f/p0, rp1 = 1.0f/p1, rp2 = 1.0f/p2;
  const int OUT_T = BQ*3*HWQ*2;
  const int OUT_Q = OUT_T + BQ*3*HWQ;
  const int gi = l >> 4;
  const int m  = l & 15;

  __threadfence();
  grid.sync();

  // ================= RK4 stage loop =========================================
  #pragma unroll 1
  for (int s = 0; s < 4; ++s) {
    // ---- inline means: waves 0-5 reduce this stage's partials ---------------
    if (w < 6) {
      const float* gp = g_part[s & 1] + w*256;
      float sm = gp[l] + gp[l+64] + gp[l+128] + gp[l+192];
      #pragma unroll
      for (int off=32; off; off >>= 1) sm += __shfl_down(sm, off);
      if (l == 0) s_mean[w] = sm * (1.0f/(float)HWQ);
    }

    const float* Tsrc = s ? g_Ts  : T0;
    const float* qsrc = s ? g_qs  : q0;
    const float* usrc = s ? g_uvs : uv0;

    #pragma unroll
    for (int bq = 0; bq < 2; ++bq) {
      // ---- staging: raw f32 state -> bf16 cells (halo rows zero) ------------
      for (int e = tid; e < TH*TW; e += 512) {
        int lr = e / TW, lc = e - lr*TW;
        int row = R0 + lr - 2;
        int col = (c0 + lc - 2) & (WW-1);
        unsigned int pk[16];
        #pragma unroll
        for (int i=0;i<16;++i) pk[i] = 0;
        if (row >= 0 && row < HH) {
          float T[3], q[3], u[3], v[3];
          #pragma unroll
          for (int k=0;k<3;++k) {
            int pix = ((bq*3+k)*HH + row)*WW + col;
            T[k] = Tsrc[pix]; q[k] = qsrc[pix];
            float2 uvv = *(const float2*)(usrc + 2*pix);
            u[k] = uvv.x; v[k] = uvv.y;
          }
          float u2[3];
          #pragma unroll
          for (int k=0;k<3;++k) u2[k] = u[k]*u[k] + v[k]*v[k];
          float ke0 = kw00*u2[0] + kw01*u2[1] + kw02*u2[2];
          float ke1 = kw10*u2[0] + kw11*u2[1] + kw12*u2[2];
          float ke2 = kw20*u2[0] + kw21*u2[1] + kw22*u2[2];
          unsigned short hs[28];
          #pragma unroll
          for (int k=0;k<3;++k) {
            hs[4*k+0] = f2bf(T[k]); hs[4*k+1] = f2bf(q[k]);
            hs[4*k+2] = f2bf(u[k]); hs[4*k+3] = f2bf(v[k]);
          }
          hs[12]=f2bf(ke0); hs[13]=f2bf(ke1); hs[14]=f2bf(ke2); hs[15]=0;
          #pragma unroll
          for (int k=0;k<3;++k) {
            hs[16+2*k] = f2bf(T[k]*u[k]); hs[17+2*k] = f2bf(T[k]*v[k]);
            hs[22+2*k] = f2bf(q[k]*u[k]); hs[23+2*k] = f2bf(q[k]*v[k]);
          }
          #pragma unroll
          for (int i=0;i<14;++i) pk[i] = hs[2*i] | ((unsigned)hs[2*i+1] << 16);
        }
        uint4* dst = (uint4*)(s_raw + e*CSTR);
        dst[0] = make_uint4(pk[0],pk[1],pk[2],pk[3]);
        dst[1] = make_uint4(pk[4],pk[5],pk[6],pk[7]);
        dst[2] = make_uint4(pk[8],pk[9],pk[10],pk[11]);
        dst[3] = make_uint4(pk[12],pk[13],pk[14],pk[15]);
      }
      __syncthreads();

      // ---- acc init: f_cor row term + mean correction ------------------------
      f32x4 acc[4];
      {
        float4 fc = *(const float4*)(g_FC + r*16 + gi*4);
        f32x4 base = (f32x4){fc.x, fc.y, fc.z, fc.w};
        #pragma unroll
        for (int k=0;k<3;++k) {
          float mk = s_mean[bq*3+k];
          float4 sk = *(const float4*)(g_S + (r*3+k)*16 + gi*4);
          base.x -= mk*sk.x; base.y -= mk*sk.y; base.z -= mk*sk.z; base.w -= mk*sk.w;
        }
        #pragma unroll
        for (int nt=0;nt<4;++nt) acc[nt] = base;
      }

      // ---- 25-tap MFMA loop: contiguous 1KB conflict-free B reads ------------
      const char* sb = s_raw;
      #pragma unroll 5
      for (int t=0;t<25;++t) {
        const int dy = t/5, dx = t%5;
        const uint4 aw = g_Wm[t*64 + l];
        const s16x8 af = __builtin_bit_cast(s16x8, aw);
        const int base = (((w+dy)*TW) + dx + m)*CSTR + gi*16;
        #pragma unroll
        for (int nt=0;nt<4;++nt) {
          const s16x8 bf = __builtin_bit_cast(s16x8,
              *(const uint4*)(sb + base + nt*(16*CSTR)));
          acc[nt] = __builtin_amdgcn_mfma_f32_16x16x32_bf16(af, bf, acc[nt], 0, 0, 0);
        }
      }

      // center values (bf16) for thermo + Coriolis
      float Tc[3], ucv[3], vcv[3];
      {
        const char* cc = sb + (((w+2)*TW) + (l+2))*CSTR;
        const uint4 c0v = *(const uint4*)cc;        // s0-7
        const uint2 c1v = *(const uint2*)(cc + 16); // s8-11
        Tc[0]=bflo(c0v.x); ucv[0]=bflo(c0v.y); vcv[0]=bfhi(c0v.y);
        Tc[1]=bflo(c0v.z); ucv[1]=bflo(c0v.w); vcv[1]=bfhi(c0v.w);
        Tc[2]=bflo(c1v.x); ucv[2]=bflo(c1v.y); vcv[2]=bfhi(c1v.y);
      }
      __syncthreads();                              // tile dead; reuse for transpose

      // transpose D fragments -> per-lane all 16 outputs (per-wave region)
      float* sf = (float*)s_raw;
      const int trb = w * (64*TRL);
      #pragma unroll
      for (int nt=0;nt<4;++nt)
        *(f32x4*)(sf + trb + (nt*16 + m)*TRL + gi*4) = acc[nt];
      float y[16];
      #pragma unroll
      for (int q=0;q<4;++q) {
        float4 v = *(const float4*)(sf + trb + l*TRL + q*4);
        y[4*q+0]=v.x; y[4*q+1]=v.y; y[4*q+2]=v.z; y[4*q+3]=v.w;
      }
      __syncthreads();                              // transpose reads done

      // ---- physics: k values --------------------------------------------------
      float kT[3], kq[3], ku[3], kv[3];
      #pragma unroll
      for (int k=0;k<3;++k) {
        kT[k] = y[3+k];
        kq[k] = y[6+k];
        ku[k] = y[9+2*k]  + fcv*vcv[k];             // Coriolis (svp collapses to this)
        kv[k] = y[10+2*k] - fcv*ucv[k];
      }
      const float oh1 = y[0]*dp0;
      const float oh2 = oh1 + y[1]*dp1;
      const float oh3 = oh2 + y[2]*dp2;
      const float om0 = 0.5f*oh1, om1 = 0.5f*(oh1+oh2), om2 = 0.5f*(oh2+oh3);
      kT[0] += om0*(roc*Tc[0]*rp0 - (Tc[1]-Tc[0])*r10);
      kT[1] += om1*(roc*Tc[1]*rp1 - (Tc[2]-Tc[0])*r20);
      kT[2] += om2*(roc*Tc[2]*rp2 - (Tc[2]-Tc[1])*r21);

      // ---- RK4 register accumulate + stage advance ----------------------------
      const float wk = (s==1 || s==2) ? 2.0f : 1.0f;
      #pragma unroll
      for (int k=0;k<3;++k) {
        if (s == 0) {
          accT[bq][k]=kT[k]; accq[bq][k]=kq[k]; accu[bq][k]=ku[k]; accv[bq][k]=kv[k];
        } else {
          accT[bq][k]+=wk*kT[k]; accq[bq][k]+=wk*kq[k];
          accu[bq][k]+=wk*ku[k]; accv[bq][k]+=wk*kv[k];
        }
      }

      if (s < 3) {
        const float an = (s==2) ? dtf : 0.5f*dtf;
        float Tn[3];
        #pragma unroll
        for (int k=0;k<3;++k) {
          const int pix = ((bq*3+k)*HH + r)*WW + c;
          Tn[k] = baseT[bq][k] + an*kT[k];
          g_Ts[pix] = Tn[k];
          g_qs[pix] = baseq[bq][k] + an*kq[k];
          g_uvs[2*pix]   = baseu[bq][k] + an*ku[k];
          g_uvs[2*pix+1] = basev[bq][k] + an*kv[k];
        }
        // partial sums of next-stage T for its mean (opposite parity buffer)
        #pragma unroll
        for (int k=0;k<3;++k) {
          float v = Tn[k];
          #pragma unroll
          for (int off=32; off; off >>= 1) v += __shfl_down(v, off);
          if (l == 0) s_red[w][k] = v;
        }
        __syncthreads();
        if (tid == 0) {
          #pragma unroll
          for (int k=0;k<3;++k) {
            float sum = 0.f;
            #pragma unroll
            for (int ww=0;ww<8;++ww) sum += s_red[ww][k];
            g_part[(s+1)&1][(bq*3+k)*256 + ry*8 + cx] = sum;
          }
        }
      } else {
        const float c6 = dtf/6.0f;
        #pragma unroll
        for (int k=0;k<3;++k) {
          const int pix = ((bq*3+k)*HH + r)*WW + c;
          out[2*pix]         = baseu[bq][k] + c6*accu[bq][k];
          out[2*pix+1]       = basev[bq][k] + c6*accv[bq][k];
          out[OUT_T + pix]   = baseT[bq][k] + c6*accT[bq][k];
          out[OUT_Q + pix]   = baseq[bq][k] + c6*accq[bq][k];
        }
      }
    } // bq

    if (s < 3) {
      __threadfence();
      grid.sync();
    }
  }
}

// -----------------------------------------------------------------------------
extern "C" void kernel_launch(void* const* d_in, const int* in_sizes, int n_in,
                              void* d_out, int out_size, void* d_ws, size_t ws_size,
                              hipStream_t stream) {
  (void)in_sizes; (void)n_in; (void)d_ws; (void)ws_size; (void)out_size;
  const float* uv0   = (const float*)d_in[0];
  const float* T0    = (const float*)d_in[1];
  const float* q0    = (const float*)d_in[2];
  const float* k_ss  = (const float*)d_in[3];
  const float* k_vs  = (const float*)d_in[4];
  const float* k_sv  = (const float*)d_in[5];
  const float* k_vv  = (const float*)d_in[6];
  const float* k_vs2 = (const float*)d_in[7];
  const float* ke_w  = (const float*)d_in[10];
  const float* f_cor = (const float*)d_in[11];
  const float* p_lev = (const float*)d_in[12];
  const float* dpv   = (const float*)d_in[13];
  const int*   dtp   = (const int*)d_in[14];
  float* out = (float*)d_out;

  void* args[] = {
    (void*)&ke_w, (void*)&f_cor, (void*)&p_lev, (void*)&dpv,
    (void*)&uv0,  (void*)&T0,    (void*)&q0,    (void*)&out,
    (void*)&dtp,
    (void*)&k_ss, (void*)&k_vs,  (void*)&k_sv,  (void*)&k_vv, (void*)&k_vs2
  };
  hipLaunchCooperativeKernel((const void*)step_kernel,
                             dim3(256,1,1), dim3(512,1,1), args, 0, stream);
}

// Round 8
// 89.321 us; speedup vs baseline: 4.1616x; 4.1616x over previous
//
#include <hip/hip_runtime.h>

#define HH 256
#define WW 512
#define BQ 2
#define HWQ (HH*WW)
#define TW 68             // LDS tile cols (64 + 4 halo)
#define TH 12             // LDS tile rows (8 out + 4 halo)
#define CSTR 64           // LDS cell stride bytes (dense) + slot swizzle
#define TRL 20            // transpose stride (dwords)

#define RGASC 287.0f
#define CPC   1004.0f

typedef float f32x4 __attribute__((ext_vector_type(4)));
typedef short s16x8 __attribute__((ext_vector_type(8)));

// ---------------- static device scratch -------------------------------------
static __device__ uint4 g_Wm[25*64];          // packed A-fragments [tap][lane]
static __device__ float g_FC[HH*16];          // f_cor conv row-term [r][o]
static __device__ float g_S [HH*3*16];        // mean-correction  [r][k][o]
static __device__ float g_part[2][6*512];     // per-block partial sums (parity dbuf)
static __device__ float g_uvs[BQ*3*HWQ*2];    // stage state
static __device__ float g_Ts [BQ*3*HWQ];
static __device__ float g_qs [BQ*3*HWQ];
static __device__ float g_aT [BQ*3*HWQ];      // RK4 accumulators
static __device__ float g_aq [BQ*3*HWQ];
static __device__ float g_auv[BQ*3*HWQ*2];

// Cell slot map (32 bf16): s0-11: [T0,q0,u0,v0, T1,q1,u1,v1, T2,q2,u2,v2]
// s12-14: KE0-2, s15: 0, s16-21: zT (T_k*u_k, T_k*v_k), s22-27: zq, s28-31: 0.
// Chunk g (16B) of the cell at tile-col lc is stored at slot (g + key(lc)) & 3,
// key(lc) = (lc + (lc>>2)) & 3. For any 16 consecutive columns the quarter-wave
// b128 start-banks {16*lc + 4*slot mod 32} cover each aligned start exactly
// twice -> conflict-free. key is nt-invariant (lc -> lc+16 adds 20 ≡ 0 mod 4).
// Output rows o: 0-2 DIV_k, 3-5 TK_k, 6-8 QK_k, 9-14 (U0,V0,U1,V1,U2,V2), 15 pad.

__device__ __forceinline__ unsigned short f2bf(float f) {   // RNE f32->bf16
  unsigned int u = __builtin_bit_cast(unsigned int, f);
  u += 0x7fffu + ((u >> 16) & 1u);
  return (unsigned short)(u >> 16);
}
__device__ __forceinline__ float bflo(unsigned int d) {
  return __builtin_bit_cast(float, d << 16);
}
__device__ __forceinline__ float bfhi(unsigned int d) {
  return __builtin_bit_cast(float, d & 0xffff0000u);
}
__device__ __forceinline__ int foMap(int o) {   // full scalar-output channel
  return (o < 3) ? 6*o + 3 : (o < 6) ? 6*(o-3) + 4 : 6*(o-6) + 5;
}

// ---------------- prelude: input-T partial means + weight packing ------------
__global__ __launch_bounds__(256) void prelude_kernel(
    const float* __restrict__ T0,
    const float* __restrict__ k_ss, const float* __restrict__ k_vs,
    const float* __restrict__ k_sv, const float* __restrict__ k_vv,
    const float* __restrict__ k_vs2, const float* __restrict__ f_cor)
{
  if (blockIdx.x < 3072) {                // meanpart: bk = bx>>9, chunk = bx&511
    int bk = blockIdx.x >> 9, chunk = blockIdx.x & 511;
    float v = T0[bk*HWQ + chunk*256 + threadIdx.x];
    int l = threadIdx.x & 63, w = threadIdx.x >> 6;
    #pragma unroll
    for (int off=32; off; off >>= 1) v += __shfl_down(v, off);
    __shared__ float sr[4];
    if (l == 0) sr[w] = v;
    __syncthreads();
    if (threadIdx.x == 0) g_part[0][bk*512 + chunk] = sr[0]+sr[1]+sr[2]+sr[3];
    return;
  }
  int tid = (blockIdx.x - 3072)*256 + threadIdx.x;
  if (tid < 1600) {                       // A-fragments g_Wm[t][lane]
    int l = tid & 63, t = tid >> 6;
    int o = l & 15, g = l >> 4;
    int dy = t/5, dx = t%5;
    unsigned short h[8];
    #pragma unroll
    for (int e=0;e<8;++e) {
      int s = 8*g + e; float val = 0.f;
      if (o < 15) {
        int fo = foMap(o), vo = o - 9;
        if (s < 12) {
          int k = s >> 2, c4 = s & 3;
          if (c4 >= 2) {                  // u_k / v_k
            int j = 2*k + (c4-2);
            val = (o<9) ? k_vs[((fo*6+j)*5+dy)*5+dx]
                        : k_vv[((vo*6+j)*5+dy)*5+dx];
          } else {                        // T_k (+fold T_anom) / q_k
            int ifull = 6*k + ((c4==0) ? 4 : 5);
            val = (o<9) ? k_ss[((fo*19+ifull)*5+dy)*5+dx]
                        : k_sv[((vo*19+ifull)*5+dy)*5+dx];
            if (c4 == 0) {
              int ia = 6*k;               // T_anom channel folded into T
              val += (o<9) ? k_ss[((fo*19+ia)*5+dy)*5+dx]
                           : k_sv[((vo*19+ia)*5+dy)*5+dx];
            }
          }
        } else if (s < 15) {              // KE_k
          int ifull = 6*(s-12) + 1;
          val = (o<9) ? k_ss[((fo*19+ifull)*5+dy)*5+dx]
                      : k_sv[((vo*19+ifull)*5+dy)*5+dx];
        } else if (s >= 16 && s < 22) {   // zT_{k,c} -> only output TK_k
          int k = (s-16)>>1, c = (s-16)&1;
          if (o == 3+k) val = k_vs2[(((6*k+4)*6 + 2*k+c)*5+dy)*5+dx];
        } else if (s >= 22 && s < 28) {   // zq_{k,c} -> only output QK_k
          int k = (s-22)>>1, c = (s-22)&1;
          if (o == 6+k) val = k_vs2[(((6*k+5)*6 + 2*k+c)*5+dy)*5+dx];
        }
      }
      h[e] = f2bf(val);
    }
    uint4 wv;
    wv.x = h[0] | ((unsigned)h[1]<<16);  wv.y = h[2] | ((unsigned)h[3]<<16);
    wv.z = h[4] | ((unsigned)h[5]<<16);  wv.w = h[6] | ((unsigned)h[7]<<16);
    g_Wm[tid] = wv;
  } else if (tid < 1600 + HH*16) {        // g_FC[r][o]: f_cor channel conv term
    int e = tid - 1600;
    int o = e & 15, r = e >> 4;
    float val = 0.f;
    if (o < 15) {
      int fo = foMap(o), vo = o - 9;
      for (int t=0;t<25;++t) {
        int dy = t/5, dx = t%5;
        int ar = r + dy - 2;
        if (ar < 0 || ar >= HH) continue;
        float f = f_cor[ar];
        float wv = (o<9) ? k_ss[((fo*19+18)*5+dy)*5+dx]
                         : k_sv[((vo*19+18)*5+dy)*5+dx];
        val += wv * f;
      }
    }
    g_FC[e] = val;
  } else if (tid < 1600 + HH*16 + HH*3*16) {  // g_S[r][k][o] mean-correction
    int e = tid - 1600 - HH*16;
    int o = e & 15; int rk = e >> 4;
    int k = rk % 3, r = rk / 3;
    float val = 0.f;
    if (o < 15) {
      int fo = foMap(o), vo = o - 9;
      int ia = 6*k;                       // T_anom weight sum over valid taps
      for (int t=0;t<25;++t) {
        int dy = t/5, dx = t%5;
        int ar = r + dy - 2;
        if (ar < 0 || ar >= HH) continue;
        val += (o<9) ? k_ss[((fo*19+ia)*5+dy)*5+dx]
                     : k_sv[((vo*19+ia)*5+dy)*5+dx];
      }
    }
    g_S[e] = val;
  }
}

// ---------------- fused stage: mean + build field + MFMA conv + RK4 ----------
__global__ __launch_bounds__(512, 4) void conv_kernel(
    const float* __restrict__ ke_w,
    const float* __restrict__ f_cor, const float* __restrict__ p_lev,
    const float* __restrict__ delta_p,
    const float* __restrict__ uv0, const float* __restrict__ T0,
    const float* __restrict__ q0,
    float* __restrict__ out, const int* __restrict__ dtp, int stage)
{
  __shared__ __align__(16) char s_raw[TH*TW*CSTR];   // 52224 B; reused for transpose
  __shared__ float s_red[8][3];
  __shared__ float s_mean[3];

  const int tid = threadIdx.x;
  const int w   = tid >> 6;                     // wave 0..7 -> output row
  const int l   = tid & 63;
  const int b   = blockIdx.z;
  const int c0  = blockIdx.x << 6;
  const int R0  = blockIdx.y << 3;
  const int r   = R0 + w;

  // ---- inline mean: waves 0-2 reduce this stage's partials ------------------
  if (w < 3) {
    const float* gp = g_part[stage & 1] + (b*3 + w)*512;
    float s;
    if (stage == 0) {
      s = gp[l] + gp[l+64] + gp[l+128] + gp[l+192]
        + gp[l+256] + gp[l+320] + gp[l+384] + gp[l+448];
    } else {
      s = gp[l] + gp[l+64] + gp[l+128] + gp[l+192];
    }
    #pragma unroll
    for (int off=32; off; off >>= 1) s += __shfl_down(s, off);
    if (l == 0) s_mean[w] = s * (1.0f/(float)HWQ);
  }

  const int useg = (stage > 0);
  const float* Tsrc = useg ? g_Ts  : T0;
  const float* qsrc = useg ? g_qs  : q0;
  const float* usrc = useg ? g_uvs : uv0;

  // ---- fused prep: raw f32 state -> bf16 cells (halo rows zero) -------------
  const float kw00=ke_w[0], kw01=ke_w[1], kw02=ke_w[2];
  const float kw10=ke_w[3], kw11=ke_w[4], kw12=ke_w[5];
  const float kw20=ke_w[6], kw21=ke_w[7], kw22=ke_w[8];
  for (int e = tid; e < TH*TW; e += 512) {
    int lr = e / TW, lc = e - lr*TW;
    int row = R0 + lr - 2;
    int col = (c0 + lc - 2) & (WW-1);
    unsigned int pk[16];
    #pragma unroll
    for (int i=0;i<16;++i) pk[i] = 0;
    if (row >= 0 && row < HH) {
      float T[3], q[3], u[3], v[3];
      #pragma unroll
      for (int k=0;k<3;++k) {
        int pix = ((b*3+k)*HH + row)*WW + col;
        T[k] = Tsrc[pix]; q[k] = qsrc[pix];
        float2 uvv = *(const float2*)(usrc + 2*pix);
        u[k] = uvv.x; v[k] = uvv.y;
      }
      float u2[3];
      #pragma unroll
      for (int k=0;k<3;++k) u2[k] = u[k]*u[k] + v[k]*v[k];
      float ke0 = kw00*u2[0] + kw01*u2[1] + kw02*u2[2];
      float ke1 = kw10*u2[0] + kw11*u2[1] + kw12*u2[2];
      float ke2 = kw20*u2[0] + kw21*u2[1] + kw22*u2[2];
      unsigned short hs[28];
      #pragma unroll
      for (int k=0;k<3;++k) {
        hs[4*k+0] = f2bf(T[k]); hs[4*k+1] = f2bf(q[k]);
        hs[4*k+2] = f2bf(u[k]); hs[4*k+3] = f2bf(v[k]);
      }
      hs[12]=f2bf(ke0); hs[13]=f2bf(ke1); hs[14]=f2bf(ke2); hs[15]=0;
      #pragma unroll
      for (int k=0;k<3;++k) {
        hs[16+2*k] = f2bf(T[k]*u[k]); hs[17+2*k] = f2bf(T[k]*v[k]);
        hs[22+2*k] = f2bf(q[k]*u[k]); hs[23+2*k] = f2bf(q[k]*v[k]);
      }
      #pragma unroll
      for (int i=0;i<14;++i) pk[i] = hs[2*i] | ((unsigned)hs[2*i+1] << 16);
    }
    const int key = (lc + (lc >> 2)) & 3;       // slot swizzle (write side)
    uint4* cell = (uint4*)(s_raw + e*CSTR);
    cell[(0+key)&3] = make_uint4(pk[0],pk[1],pk[2],pk[3]);
    cell[(1+key)&3] = make_uint4(pk[4],pk[5],pk[6],pk[7]);
    cell[(2+key)&3] = make_uint4(pk[8],pk[9],pk[10],pk[11]);
    cell[(3+key)&3] = make_uint4(pk[12],pk[13],pk[14],pk[15]);
  }
  __syncthreads();

  // ---- acc init: f_cor row term + mean correction ---------------------------
  const int gi = l >> 4;
  const int m  = l & 15;
  f32x4 acc[4];
  {
    float4 fc = *(const float4*)(g_FC + r*16 + gi*4);
    f32x4 base = (f32x4){fc.x, fc.y, fc.z, fc.w};
    #pragma unroll
    for (int k=0;k<3;++k) {
      float mk = s_mean[k];
      float4 sk = *(const float4*)(g_S + (r*3+k)*16 + gi*4);
      base.x -= mk*sk.x; base.y -= mk*sk.y; base.z -= mk*sk.z; base.w -= mk*sk.w;
    }
    #pragma unroll
    for (int nt=0;nt<4;++nt) acc[nt] = base;
  }

  // ---- 25-tap MFMA loop: swizzled conflict-free B reads ----------------------
  const char* sb = s_raw;
  #pragma unroll 5
  for (int t=0;t<25;++t) {
    const int dy = t/5, dx = t%5;
    const uint4 aw = g_Wm[t*64 + l];
    const s16x8 af = __builtin_bit_cast(s16x8, aw);
    const int lc0  = dx + m;
    const int slot = (gi + lc0 + (lc0 >> 2)) & 3;   // nt-invariant key
    const int base = (((w+dy)*TW) + lc0)*CSTR + slot*16;
    #pragma unroll
    for (int nt=0;nt<4;++nt) {
      const s16x8 bf = __builtin_bit_cast(s16x8,
          *(const uint4*)(sb + base + nt*(16*CSTR)));
      acc[nt] = __builtin_amdgcn_mfma_f32_16x16x32_bf16(af, bf, acc[nt], 0, 0, 0);
    }
  }

  // center values (bf16) for thermo + Coriolis (chunks 0,1 at swizzled slots)
  float Tc[3], ucv[3], vcv[3];
  {
    const int lcc = l + 2;
    const int keyc = (lcc + (lcc >> 2)) & 3;
    const char* cc = sb + (((w+2)*TW) + lcc)*CSTR;
    const uint4 c0v = *(const uint4*)(cc + ((0+keyc)&3)*16);  // s0-7
    const uint2 c1v = *(const uint2*)(cc + ((1+keyc)&3)*16);  // s8-11
    Tc[0]=bflo(c0v.x); ucv[0]=bflo(c0v.y); vcv[0]=bfhi(c0v.y);
    Tc[1]=bflo(c0v.z); ucv[1]=bflo(c0v.w); vcv[1]=bfhi(c0v.w);
    Tc[2]=bflo(c1v.x); ucv[2]=bflo(c1v.y); vcv[2]=bfhi(c1v.y);
  }
  __syncthreads();                              // tile dead; reuse for transpose

  // transpose D fragments -> per-lane all 16 outputs (per-wave region)
  float* sf = (float*)s_raw;
  const int trb = w * (64*TRL);
  #pragma unroll
  for (int nt=0;nt<4;++nt)
    *(f32x4*)(sf + trb + (nt*16 + m)*TRL + gi*4) = acc[nt];
  float y[16];
  #pragma unroll
  for (int q=0;q<4;++q) {
    float4 v = *(const float4*)(sf + trb + l*TRL + q*4);
    y[4*q+0]=v.x; y[4*q+1]=v.y; y[4*q+2]=v.z; y[4*q+3]=v.w;
  }

  // ----------------- physics + RK4 ------------------------------------------
  const int c = c0 + l;
  const float fcv = f_cor[r];
  const float dtf = (float)(*dtp);
  const float an  = (stage==2) ? dtf : 0.5f*dtf;
  const float c6  = dtf/6.0f;
  const float p0=p_lev[0], p1=p_lev[1], p2=p_lev[2];
  const float dp0=delta_p[0], dp1=delta_p[1], dp2=delta_p[2];
  const float r10 = 1.0f/(p1-p0), r20 = 1.0f/(p2-p0), r21 = 1.0f/(p2-p1);
  const float roc = RGASC/CPC;
  const float rp0 = 1.0f/p0, rp1 = 1.0f/p1, rp2 = 1.0f/p2;
  const int OUT_T = BQ*3*HWQ*2;
  const int OUT_Q = OUT_T + BQ*3*HWQ;

  float kT[3], kq[3], ku[3], kv[3];
  #pragma unroll
  for (int k=0;k<3;++k) {
    kT[k] = y[3+k];
    kq[k] = y[6+k];
    ku[k] = y[9+2*k]  + fcv*vcv[k];             // Coriolis (svp collapses to this)
    kv[k] = y[10+2*k] - fcv*ucv[k];
  }
  const float oh1 = y[0]*dp0;
  const float oh2 = oh1 + y[1]*dp1;
  const float oh3 = oh2 + y[2]*dp2;
  const float om0 = 0.5f*oh1, om1 = 0.5f*(oh1+oh2), om2 = 0.5f*(oh2+oh3);
  kT[0] += om0*(roc*Tc[0]*rp0 - (Tc[1]-Tc[0])*r10);
  kT[1] += om1*(roc*Tc[1]*rp1 - (Tc[2]-Tc[0])*r20);
  kT[2] += om2*(roc*Tc[2]*rp2 - (Tc[2]-Tc[1])*r21);

  float Tn[3];
  #pragma unroll
  for (int k=0;k<3;++k) {
    const int pT = ((b*3+k)*HH + r)*WW + c;
    const int pU = pT*2;
    if (stage == 0) {
      g_aT[pT] = kT[k];  g_aq[pT] = kq[k];
      g_auv[pU] = ku[k]; g_auv[pU+1] = kv[k];
      Tn[k]      = T0[pT] + an*kT[k];
      g_Ts[pT]   = Tn[k];
      g_qs[pT]   = q0[pT] + an*kq[k];
      g_uvs[pU]   = uv0[pU]   + an*ku[k];
      g_uvs[pU+1] = uv0[pU+1] + an*kv[k];
    } else if (stage < 3) {
      g_aT[pT] += 2.0f*kT[k];  g_aq[pT] += 2.0f*kq[k];
      g_auv[pU] += 2.0f*ku[k]; g_auv[pU+1] += 2.0f*kv[k];
      Tn[k]      = T0[pT] + an*kT[k];
      g_Ts[pT]   = Tn[k];
      g_qs[pT]   = q0[pT] + an*kq[k];
      g_uvs[pU]   = uv0[pU]   + an*ku[k];
      g_uvs[pU+1] = uv0[pU+1] + an*kv[k];
    } else {
      out[pU]         = uv0[pU]   + c6*(g_auv[pU]   + ku[k]);
      out[pU+1]       = uv0[pU+1] + c6*(g_auv[pU+1] + kv[k]);
      out[OUT_T + pT] = T0[pT]    + c6*(g_aT[pT] + kT[k]);
      out[OUT_Q + pT] = q0[pT]    + c6*(g_aq[pT] + kq[k]);
    }
  }

  // partial sums of next-stage T for the mean (write opposite parity buffer)
  if (stage < 3) {
    #pragma unroll
    for (int k=0;k<3;++k) {
      float v = Tn[k];
      #pragma unroll
      for (int off=32; off; off >>= 1) v += __shfl_down(v, off);
      if (l == 0) s_red[w][k] = v;
    }
    __syncthreads();
    if (tid == 0) {
      #pragma unroll
      for (int k=0;k<3;++k) {
        float s = 0.f;
        #pragma unroll
        for (int ww=0;ww<8;++ww) s += s_red[ww][k];
        g_part[(stage & 1) ^ 1][(b*3+k)*512 + blockIdx.y*8 + blockIdx.x] = s;
      }
    }
  }
}

// -----------------------------------------------------------------------------
extern "C" void kernel_launch(void* const* d_in, const int* in_sizes, int n_in,
                              void* d_out, int out_size, void* d_ws, size_t ws_size,
                              hipStream_t stream) {
  (void)in_sizes; (void)n_in; (void)d_ws; (void)ws_size; (void)out_size;
  const float* uv0   = (const float*)d_in[0];
  const float* T0    = (const float*)d_in[1];
  const float* q0    = (const float*)d_in[2];
  const float* k_ss  = (const float*)d_in[3];
  const float* k_vs  = (const float*)d_in[4];
  const float* k_sv  = (const float*)d_in[5];
  const float* k_vv  = (const float*)d_in[6];
  const float* k_vs2 = (const float*)d_in[7];
  const float* ke_w  = (const float*)d_in[10];
  const float* f_cor = (const float*)d_in[11];
  const float* p_lev = (const float*)d_in[12];
  const float* dpv   = (const float*)d_in[13];
  const int*   dtp   = (const int*)d_in[14];
  float* out = (float*)d_out;

  prelude_kernel<<<3143, 256, 0, stream>>>(T0, k_ss, k_vs, k_sv, k_vv, k_vs2, f_cor);

  for (int st = 0; st < 4; ++st) {
    conv_kernel<<<dim3(8,32,2), 512, 0, stream>>>(
        ke_w, f_cor, p_lev, dpv, uv0, T0, q0, out, dtp, st);
  }
}